// Round 5
// baseline (209.727 us; speedup 1.0000x reference)
//
#include <hip/hip_runtime.h>

// OnlineNorm: EMA mean/var over T, then (x - m) / (4v + eps).
// x (16, 3000, 513) fp32.
//
// Ladder: R4 (1 col/thread, depth-2) 81 us @ 3.20 TB/s.
//         R5 (4 cols/thread, 2400 waves) 96 us @ 2.6 -> REGRESSION (TLP loss).
//         R6 (depth-4) 78.5 us @ 3.25 TB/s -> depth null.
//         R7 (contiguous per-block streams, 1KB transactions) 81 us @ 3.05
//            -> contiguity null; FETCH dropped 147->138 with no time gain.
// Conclusion: ~3.0-3.3 TB/s is a structural plateau for this op on this
// chip -- four independent concurrency/pattern levers all nulled. Time is
// now reducible only via BYTES.
// R8: amortize the warm-up. CHUNK 40 -> 120 (T%120==0 -> 25 chunks),
// WARM=64 unchanged (identical numerics/absmax). Row-read ratio drops
// 2.58 -> 1.51 (attempted reads 254 -> 149 MB); total rows touched x0.70.
// Structure otherwise byte-identical to R6: 1 col/thread, 256-thread
// blocks, grid 33x25 (3300 waves -- R7 showed 35% occupancy is null),
// depth-4 pipeline, per batch: compute -> prefetch loads -> stores
// (in-order vmcnt: load-waits never wait on store acks).
// Predicted: FETCH ~110-125 MB, dur 55-68 us at pinned ~3.1 TB/s.
// Falsifier: dur ~78 us -> per-chunk latency floor, pivot to LDS staging.

#define EPS 1e-12f

constexpr int B = 16;
constexpr int T = 3000;
constexpr int F = 513;
constexpr int CHUNK = 120;      // T % CHUNK == 0 -> 25 chunks
constexpr int WARM = 64;        // multiple of BT
constexpr int NC = T / CHUNK;   // 25
constexpr int BT = 8;           // t-steps per pipelined batch

__global__ __launch_bounds__(256, 7)
void OnlineNorm_11982958756550_kernel(
    const float* __restrict__ x,
    const float* __restrict__ rmean,   // (F)
    const float* __restrict__ rvar,    // (F)
    const float* __restrict__ alpha_p, // (1)
    float* __restrict__ out)
{
    const int idx = blockIdx.x * 256 + threadIdx.x;
    if (idx >= B * F) return;          // only last x-block partially active
    const int c = blockIdx.y;
    const int f = idx % F;
    const int b = idx / F;

    const float a = alpha_p[0];
    const float om_a = 1.0f - a;

    const int w_start = c * CHUNK;
    int t0 = w_start - WARM;
    float m, v;
    if (t0 <= 0) { t0 = 0; m = rmean[f]; v = rvar[f]; }
    else         { m = 0.0f; v = 0.0f; }   // decays to 3.6e-5 by w_start

    const int nrows = w_start + CHUNK - t0;   // 120 (c=0) / 184
    const int nb = nrows / BT;                // 15 / 23 batches (>= 5)
    const int wb = (w_start - t0) / BT;       // 0 / 8 warmup batches

    const size_t cs = (size_t)BT * F;         // batch stride (elements)
    const float* lp = x   + (size_t)b * T * F + (size_t)t0 * F + f;
    const float* lend = lp + (size_t)nb * cs;
    float*       op = out + (size_t)b * T * F + (size_t)w_start * F + f;

    float bufA[BT], bufB[BT], bufC[BT], bufD[BT];

    // ---- prologue: 4 batches in flight (nb >= 15 always) ----
    #pragma unroll
    for (int i = 0; i < BT; ++i) bufA[i] = lp[(size_t)i * F];
    lp += cs;
    #pragma unroll
    for (int i = 0; i < BT; ++i) bufB[i] = lp[(size_t)i * F];
    lp += cs;
    #pragma unroll
    for (int i = 0; i < BT; ++i) bufC[i] = lp[(size_t)i * F];
    lp += cs;
    #pragma unroll
    for (int i = 0; i < BT; ++i) bufD[i] = lp[(size_t)i * F];
    lp += cs;

    auto process = [&](float (&buf)[BT], int k) {
        const bool is_out = (k >= wb);   // uniform per block
        float r[BT];
        #pragma unroll
        for (int i = 0; i < BT; ++i) {
            const float e = buf[i] - m;
            m = fmaf(a, e, m);                  // m = (1-a)m + a x
            const float d = e * om_a;           // d = x - m_new
            v = fmaf(a, fmaf(d, d, -v), v);     // v = (1-a)v + a d^2
            if (is_out)
                r[i] = d * __builtin_amdgcn_rcpf(fmaf(v, 4.0f, EPS));
        }
        // prefetch batch k+4 BEFORE issuing stores (in-order vmcnt:
        // later load-waits must not wait on store acks)
        if (lp < lend) {
            #pragma unroll
            for (int i = 0; i < BT; ++i) buf[i] = lp[(size_t)i * F];
            lp += cs;
        }
        if (is_out) {
            #pragma unroll
            for (int i = 0; i < BT; ++i) op[(size_t)i * F] = r[i];
            op += cs;
        }
    };

    int k = 0;
    while (true) {
        process(bufA, k); ++k; if (k >= nb) break;
        process(bufB, k); ++k; if (k >= nb) break;
        process(bufC, k); ++k; if (k >= nb) break;
        process(bufD, k); ++k; if (k >= nb) break;
    }
}

extern "C" void kernel_launch(void* const* d_in, const int* in_sizes, int n_in,
                              void* d_out, int out_size, void* d_ws, size_t ws_size,
                              hipStream_t stream) {
    const float* x      = (const float*)d_in[0];
    const float* rmean  = (const float*)d_in[1];
    const float* rvar   = (const float*)d_in[2];
    const float* alpha  = (const float*)d_in[3];
    float* out = (float*)d_out;

    const int bf = B * F;                       // 8208
    dim3 block(256);
    dim3 grid((bf + 255) / 256, NC);            // 33 x 25 = 825 blocks
    OnlineNorm_11982958756550_kernel<<<grid, block, 0, stream>>>(
        x, rmean, rvar, alpha, out);
}

// Round 6
// 202.018 us; speedup vs baseline: 1.0382x; 1.0382x over previous
//
#include <hip/hip_runtime.h>

// OnlineNorm: EMA mean/var over T, then (x - m) / (4v + eps).
// x (16, 3000, 513) fp32.
//
// Ladder: R4 81us/259MB/57%occ; R6 (depth-4) 78.5us/256MB; R7 (contiguous
// streams) 81us/249MB/35%; R8 (CHUNK=120, bytes x0.75) 82us/192MB/24%.
// Time pinned ~80us independent of bytes, occupancy, depth, contiguity,
// rows-per-wave. Shared trait of ALL rounds: every VMEM instr moves 256B
// (scalar dword/lane; fixed-column threads at row stride 2052B). The 6.3TB/s
// ceiling was measured with 1KB/instr float4. R5's "wide" memcpy loads were
// 4B-aligned (2052%16=4) -> compiler split to scalar dwords; wide loads were
// never actually tested.
// R9: test VMEM-request-rate theory. Block=(b,chunk); stream the window
// LINEARLY (ignore row structure) with aligned float4 loads (window start
// t0*2052B, t0 mult of 8 -> 16B-aligned; batch = 8 rows = 16416B) into
// double-buffered LDS; compute reads columns from LDS (consecutive lanes ->
// consecutive banks, conflict-free). Read-side VMEM instrs /4. Stores stay
// scalar (separate lever). CHUNK=40 -> byte-identical to R6 for clean A/B.
// Predicted: dur 78.5 -> 55-65us if request-rate-bound; ~80us -> granularity
// exonerated, wall established.

#define EPS 1e-12f

constexpr int B = 16;
constexpr int T = 3000;
constexpr int F = 513;          // row = 2052 B
constexpr int CHUNK = 40;       // T % CHUNK == 0 -> 75 chunks
constexpr int WARM = 64;        // multiple of BT
constexpr int NC = T / CHUNK;   // 75
constexpr int BT = 8;           // rows per staged batch
constexpr int BWF = BT * F;     // 4104 floats = 16416 B per batch (16-aligned)

__global__ __launch_bounds__(256, 4)
void OnlineNorm_11982958756550_kernel(
    const float* __restrict__ x,
    const float* __restrict__ rmean,   // (F)
    const float* __restrict__ rvar,    // (F)
    const float* __restrict__ alpha_p, // (1)
    float* __restrict__ out)
{
    __shared__ float s[2][BWF];        // 32832 B -> 4 blocks/CU

    const int b = blockIdx.x;
    const int c = blockIdx.y;
    const int r = threadIdx.x;         // chains: f0=r, f1=256+r, f2=512 (r==255)

    const float a = alpha_p[0];
    const float om_a = 1.0f - a;

    const int w_start = c * CHUNK;
    int t0 = w_start - WARM;
    const bool cold = (t0 <= 0);
    if (cold) t0 = 0;
    const int nrows = w_start + CHUNK - t0;   // 40 / 80 / 104
    const int nb = nrows / BT;                // 5 / 10 / 13
    const int wb = (w_start - t0) / BT;       // 0 / 5 / 8

    float m0, v0, m1, v1, m2, v2;
    if (cold) {
        m0 = rmean[r];       v0 = rvar[r];
        m1 = rmean[256 + r]; v1 = rvar[256 + r];
        m2 = rmean[512];     v2 = rvar[512];
    } else {
        m0 = v0 = m1 = v1 = m2 = v2 = 0.0f;   // decays to 3.6e-5 by w_start
    }

    const size_t base = (size_t)b * T * F;
    const float* gwin = x + base + (size_t)t0 * F;   // 16B-aligned (t0 mult of 8)
    float*       op   = out + base + (size_t)w_start * F;

    float4 q0, q1, q2, q3;    // staging regs: 64 B/thread -> 1KB per wave-instr
    float  tv;                // ragged tail: words [4096,4104) of each batch

    auto stage_load = [&](int j) {
        const float4* gp = (const float4*)(gwin + (size_t)j * BWF);
        q0 = gp[r];
        q1 = gp[r + 256];
        q2 = gp[r + 512];
        q3 = gp[r + 768];
        tv = (r < 8) ? (gwin + (size_t)j * BWF)[4096 + r] : 0.0f;
    };
    auto stage_write = [&](int buf) {
        float4* sp = (float4*)(s[buf]);
        sp[r]       = q0;
        sp[r + 256] = q1;
        sp[r + 512] = q2;
        sp[r + 768] = q3;
        if (r < 8) s[buf][4096 + r] = tv;
    };

    // ---- prologue: batch 0 into buffer 0 ----
    stage_load(0);
    stage_write(0);
    __syncthreads();

    int cur = 0;
    for (int k = 0; k < nb; ++k) {
        const bool more = (k + 1 < nb);
        if (more) stage_load(k + 1);          // issue early; vmcnt waits land
                                              // just before stage_write below
        const bool is_out = (k >= wb);        // uniform per block
        const float* sb = s[cur];
        float r0[BT], r1[BT], r2[BT];
        #pragma unroll
        for (int i = 0; i < BT; ++i) {
            const float x0 = sb[i * F + r];
            const float x1 = sb[i * F + 256 + r];
            const float e0 = x0 - m0;
            m0 = fmaf(a, e0, m0);
            const float d0 = e0 * om_a;
            v0 = fmaf(a, fmaf(d0, d0, -v0), v0);
            const float e1 = x1 - m1;
            m1 = fmaf(a, e1, m1);
            const float d1 = e1 * om_a;
            v1 = fmaf(a, fmaf(d1, d1, -v1), v1);
            if (is_out) {
                r0[i] = d0 * __builtin_amdgcn_rcpf(fmaf(v0, 4.0f, EPS));
                r1[i] = d1 * __builtin_amdgcn_rcpf(fmaf(v1, 4.0f, EPS));
            }
        }
        if (r == 255) {                       // leftover column f=512
            #pragma unroll
            for (int i = 0; i < BT; ++i) {
                const float x2 = sb[i * F + 512];
                const float e2 = x2 - m2;
                m2 = fmaf(a, e2, m2);
                const float d2 = e2 * om_a;
                v2 = fmaf(a, fmaf(d2, d2, -v2), v2);
                if (is_out)
                    r2[i] = d2 * __builtin_amdgcn_rcpf(fmaf(v2, 4.0f, EPS));
            }
        }
        if (is_out) {
            #pragma unroll
            for (int i = 0; i < BT; ++i) {
                op[(size_t)i * F + r]       = r0[i];
                op[(size_t)i * F + 256 + r] = r1[i];
            }
            if (r == 255) {
                #pragma unroll
                for (int i = 0; i < BT; ++i) op[(size_t)i * F + 512] = r2[i];
            }
            op += (size_t)BT * F;
        }
        if (more) stage_write(cur ^ 1);       // batch k+1 -> other buffer
        __syncthreads();                      // drains vmcnt/lgkm: LDS ready
        cur ^= 1;
    }
}

extern "C" void kernel_launch(void* const* d_in, const int* in_sizes, int n_in,
                              void* d_out, int out_size, void* d_ws, size_t ws_size,
                              hipStream_t stream) {
    const float* x      = (const float*)d_in[0];
    const float* rmean  = (const float*)d_in[1];
    const float* rvar   = (const float*)d_in[2];
    const float* alpha  = (const float*)d_in[3];
    float* out = (float*)d_out;

    dim3 block(256);
    dim3 grid(B, NC);                  // 16 x 75 = 1200 blocks
    OnlineNorm_11982958756550_kernel<<<grid, block, 0, stream>>>(
        x, rmean, rvar, alpha, out);
}

// Round 7
// 200.728 us; speedup vs baseline: 1.0448x; 1.0064x over previous
//
#include <hip/hip_runtime.h>

// OnlineNorm: EMA mean/var over T, then (x - m) / (4v + eps).
// x (16, 3000, 513) fp32.
//
// Null ledger (dispatch time pinned ~80us through all of):
//   R6 depth 2->4            (+1.5%)        R7 contiguous streams   (null)
//   R8 bytes x0.75           (null!)        R9 float4 loads via LDS (null)
//   occupancy 24%..57% across rounds        (null)
// Invariant never tested: ALL rounds store scalar dwords (4B/lane).
// Store-bound theory fits every point: write throughput identically
// 98.5MB/80us = 1.23 TB/s in every round; read-side cuts (R8 bytes,
// R9 instrs/4) never moved time. The 6.3TB/s copy ubench is float4 on
// BOTH sides.
// R10: R9's load path verbatim (float4 -> LDS in, double-buffered; compute
// chains f=r / f=256+r, conflict-free) + LDS OUTPUT transpose: results
// scatter to so[] (lane-consecutive, conflict-free), barrier, cooperative
// linear float4 stores of the 8-row output window (1026 float4/batch,
// 16B-aligned: b*T*F*4, 40c*2052, 8j*2052 all = 0 mod 16). Store instrs /4.
// LDS 49.2KB -> 3 blocks/CU (occupancy proven null).
// Predicted: dur 55-65us if store-granularity-bound; ~80us -> declare
// structural plateau (bytes already within 10% of the 197MB floor).

#define EPS 1e-12f

constexpr int B = 16;
constexpr int T = 3000;
constexpr int F = 513;          // row = 2052 B
constexpr int CHUNK = 40;       // T % CHUNK == 0 -> 75 chunks
constexpr int WARM = 64;        // multiple of BT
constexpr int NC = T / CHUNK;   // 75
constexpr int BT = 8;           // rows per staged batch
constexpr int BWF = BT * F;     // 4104 floats = 16416 B per batch

__global__ __launch_bounds__(256, 3)
void OnlineNorm_11982958756550_kernel(
    const float* __restrict__ x,
    const float* __restrict__ rmean,   // (F)
    const float* __restrict__ rvar,    // (F)
    const float* __restrict__ alpha_p, // (1)
    float* __restrict__ out)
{
    __shared__ float si[2][BWF];       // input staging (32832 B)
    __shared__ float so[BWF];          // output staging (16416 B)

    const int b = blockIdx.x;
    const int c = blockIdx.y;
    const int r = threadIdx.x;         // chains: f0=r, f1=256+r, f2=512 (r==255)

    const float a = alpha_p[0];
    const float om_a = 1.0f - a;

    const int w_start = c * CHUNK;
    int t0 = w_start - WARM;
    const bool cold = (t0 <= 0);
    if (cold) t0 = 0;
    const int nrows = w_start + CHUNK - t0;   // 40 / 80 / 104
    const int nb = nrows / BT;                // 5 / 10 / 13
    const int wb = (w_start - t0) / BT;       // 0 / 5 / 8

    float m0, v0, m1, v1, m2, v2;
    if (cold) {
        m0 = rmean[r];       v0 = rvar[r];
        m1 = rmean[256 + r]; v1 = rvar[256 + r];
        m2 = rmean[512];     v2 = rvar[512];
    } else {
        m0 = v0 = m1 = v1 = m2 = v2 = 0.0f;   // decays to 3.6e-5 by w_start
    }

    const size_t base = (size_t)b * T * F;
    const float* gwin = x + base + (size_t)t0 * F;   // 16B-aligned (t0 mult of 8)

    float4 q0, q1, q2, q3;    // staging regs: 64 B/thread -> 1KB per wave-instr
    float  tv;                // ragged tail: floats [4096,4104) of each batch

    auto stage_load = [&](int j) {
        const float4* gp = (const float4*)(gwin + (size_t)j * BWF);
        q0 = gp[r];
        q1 = gp[r + 256];
        q2 = gp[r + 512];
        q3 = gp[r + 768];
        tv = (r < 8) ? (gwin + (size_t)j * BWF)[4096 + r] : 0.0f;
    };
    auto stage_write = [&](int buf) {
        float4* sp = (float4*)(si[buf]);
        sp[r]       = q0;
        sp[r + 256] = q1;
        sp[r + 512] = q2;
        sp[r + 768] = q3;
        if (r < 8) si[buf][4096 + r] = tv;
    };

    // ---- prologue: batch 0 into buffer 0 ----
    stage_load(0);
    stage_write(0);
    __syncthreads();

    int cur = 0;
    for (int k = 0; k < nb; ++k) {
        const bool more = (k + 1 < nb);
        if (more) stage_load(k + 1);          // loads enter vmcnt queue FIRST:
                                              // stage_write's wait never waits
                                              // on this batch's store acks
        const bool is_out = (k >= wb);        // uniform per block
        const float* sb = si[cur];
        float r0[BT], r1[BT], r2[BT];
        #pragma unroll
        for (int i = 0; i < BT; ++i) {
            const float x0 = sb[i * F + r];
            const float x1 = sb[i * F + 256 + r];
            const float e0 = x0 - m0;
            m0 = fmaf(a, e0, m0);
            const float d0 = e0 * om_a;
            v0 = fmaf(a, fmaf(d0, d0, -v0), v0);
            const float e1 = x1 - m1;
            m1 = fmaf(a, e1, m1);
            const float d1 = e1 * om_a;
            v1 = fmaf(a, fmaf(d1, d1, -v1), v1);
            if (is_out) {
                r0[i] = d0 * __builtin_amdgcn_rcpf(fmaf(v0, 4.0f, EPS));
                r1[i] = d1 * __builtin_amdgcn_rcpf(fmaf(v1, 4.0f, EPS));
            }
        }
        if (r == 255) {                       // leftover column f=512
            #pragma unroll
            for (int i = 0; i < BT; ++i) {
                const float x2 = sb[i * F + 512];
                const float e2 = x2 - m2;
                m2 = fmaf(a, e2, m2);
                const float d2 = e2 * om_a;
                v2 = fmaf(a, fmaf(d2, d2, -v2), v2);
                if (is_out)
                    r2[i] = d2 * __builtin_amdgcn_rcpf(fmaf(v2, 4.0f, EPS));
            }
        }
        if (is_out) {
            // transpose through LDS: lane-consecutive writes, conflict-free
            #pragma unroll
            for (int i = 0; i < BT; ++i) {
                so[i * F + r]       = r0[i];
                so[i * F + 256 + r] = r1[i];
            }
            if (r == 255) {
                #pragma unroll
                for (int i = 0; i < BT; ++i) so[i * F + 512] = r2[i];
            }
            __syncthreads();                  // so[] complete
            // cooperative wide store: 1026 aligned float4 (16416 B window)
            float4* og = (float4*)(out + base
                         + (size_t)(w_start + (k - wb) * BT) * F);
            const float4* sof = (const float4*)so;
            og[r]       = sof[r];
            og[r + 256] = sof[r + 256];
            og[r + 512] = sof[r + 512];
            og[r + 768] = sof[r + 768];
            if (r < 2) og[1024 + r] = sof[1024 + r];
        }
        if (more) stage_write(cur ^ 1);       // batch k+1 -> other buffer
        __syncthreads();                      // LDS ready; also separates so[]
                                              // reads from next batch's writes
        cur ^= 1;
    }
}

extern "C" void kernel_launch(void* const* d_in, const int* in_sizes, int n_in,
                              void* d_out, int out_size, void* d_ws, size_t ws_size,
                              hipStream_t stream) {
    const float* x      = (const float*)d_in[0];
    const float* rmean  = (const float*)d_in[1];
    const float* rvar   = (const float*)d_in[2];
    const float* alpha  = (const float*)d_in[3];
    float* out = (float*)d_out;

    dim3 block(256);
    dim3 grid(B, NC);                  // 16 x 75 = 1200 blocks
    OnlineNorm_11982958756550_kernel<<<grid, block, 0, stream>>>(
        x, rmean, rvar, alpha, out);
}